// Round 1
// baseline (448.428 us; speedup 1.0000x reference)
//
#include <hip/hip_runtime.h>
#include <hip/hip_bf16.h>
#include <math.h>

// Problem constants
#define T_ 8192   // B*S tokens
#define D_ 1024
#define E_ 16
#define H_ 2048

__device__ __forceinline__ float wave_sum(float v) {
    #pragma unroll
    for (int m = 32; m >= 1; m >>= 1) v += __shfl_xor(v, m, 64);
    return v;
}
__device__ __forceinline__ float wave_max(float v) {
    #pragma unroll
    for (int m = 32; m >= 1; m >>= 1) v = fmaxf(v, __shfl_xor(v, m, 64));
    return v;
}

// K1: logits[t][e] = dot(x[t], router_w[e])   (TEMP = 1)
// 256 blocks x 256 threads; block stages full router_w (64KB) in LDS;
// each wave handles 8 tokens sequentially.
__global__ __launch_bounds__(256) void k1_logits(const float* __restrict__ x,
                                                 const float* __restrict__ rw,
                                                 float* __restrict__ logits) {
    __shared__ float rw_lds[E_ * D_];
    for (int i = threadIdx.x; i < E_ * D_; i += 256) rw_lds[i] = rw[i];
    __syncthreads();
    const int wave = threadIdx.x >> 6, lane = threadIdx.x & 63;
    const int t0 = blockIdx.x * 32 + wave * 8;
    const float4* rl = (const float4*)rw_lds;
    for (int ti = 0; ti < 8; ++ti) {
        const int t = t0 + ti;
        const float4* xr = (const float4*)(x + (size_t)t * D_);
        float4 xv[4];
        #pragma unroll
        for (int k = 0; k < 4; ++k) xv[k] = xr[lane + 64 * k];
        float my = 0.0f;
        #pragma unroll
        for (int e = 0; e < E_; ++e) {
            float s = 0.0f;
            #pragma unroll
            for (int k = 0; k < 4; ++k) {
                float4 wv = rl[e * 256 + lane + 64 * k];
                s += xv[k].x * wv.x + xv[k].y * wv.y + xv[k].z * wv.z + xv[k].w * wv.w;
            }
            s = wave_sum(s);
            if (lane == e) my = s;
        }
        if (lane < E_) logits[(size_t)t * E_ + lane] = my;
    }
}

// K2a: per-expert column max & sum(exp) over all T tokens. 16 blocks.
__global__ __launch_bounds__(256) void k2a_colstats(const float* __restrict__ logits,
                                                    float* __restrict__ colmax,
                                                    float* __restrict__ colsum) {
    const int e = blockIdx.x, tid = threadIdx.x;
    float m = -1e30f;
    for (int t = tid; t < T_; t += 256) m = fmaxf(m, logits[(size_t)t * E_ + e]);
    m = wave_max(m);
    __shared__ float red[4];
    if ((tid & 63) == 0) red[tid >> 6] = m;
    __syncthreads();
    m = fmaxf(fmaxf(red[0], red[1]), fmaxf(red[2], red[3]));
    __syncthreads();
    float s = 0.0f;
    for (int t = tid; t < T_; t += 256) s += expf(logits[(size_t)t * E_ + e] - m);
    s = wave_sum(s);
    if ((tid & 63) == 0) red[tid >> 6] = s;
    __syncthreads();
    if (tid == 0) {
        colmax[e] = m;
        colsum[e] = red[0] + red[1] + red[2] + red[3];
    }
}

// K2b: per-token combine softmax, store combine; accumulate mean_usage sums
// and entropy sum via wave-reduce + atomics. 32 blocks x 256.
__global__ __launch_bounds__(256) void k2b_combine(const float* __restrict__ logits,
                                                   float* __restrict__ combine,
                                                   float* __restrict__ musum,
                                                   float* __restrict__ entacc) {
    const int t = blockIdx.x * 256 + threadIdx.x;
    const int lane = threadIdx.x & 63;
    float l[E_];
    const float4* lr = (const float4*)(logits + (size_t)t * E_);
    #pragma unroll
    for (int q = 0; q < 4; ++q) {
        float4 v = lr[q];
        l[q * 4 + 0] = v.x; l[q * 4 + 1] = v.y; l[q * 4 + 2] = v.z; l[q * 4 + 3] = v.w;
    }
    float m = l[0];
    #pragma unroll
    for (int e = 1; e < E_; ++e) m = fmaxf(m, l[e]);
    float s = 0.0f;
    float c[E_];
    #pragma unroll
    for (int e = 0; e < E_; ++e) { c[e] = expf(l[e] - m); s += c[e]; }
    const float inv = 1.0f / s;
    float ent = 0.0f;
    #pragma unroll
    for (int e = 0; e < E_; ++e) {
        c[e] *= inv;
        ent -= c[e] * logf(c[e] + 1e-8f);
    }
    float4* cw = (float4*)(combine + (size_t)t * E_);
    #pragma unroll
    for (int q = 0; q < 4; ++q) {
        float4 v = { c[q * 4 + 0], c[q * 4 + 1], c[q * 4 + 2], c[q * 4 + 3] };
        cw[q] = v;
    }
    #pragma unroll
    for (int e = 0; e < E_; ++e) {
        float v = wave_sum(c[e]);
        if (lane == 0) atomicAdd(&musum[e], v);
    }
    float ev = wave_sum(ent);
    if (lane == 0) atomicAdd(entacc, ev);
}

// K3: slots[e][d] = sum_t dispatch[t][e] * x[t][d]
// grid (4 d-chunks, 64 t-chunks) x 256 threads; partial acc + atomicAdd.
__global__ __launch_bounds__(256) void k3_slots(const float* __restrict__ x,
                                                const float* __restrict__ logits,
                                                const float* __restrict__ colmax,
                                                const float* __restrict__ colsum,
                                                float* __restrict__ slots) {
    const int tid = threadIdx.x;
    __shared__ float disp[128 * E_];
    __shared__ float cm[E_], cs[E_];
    if (tid < E_) { cm[tid] = colmax[tid]; cs[tid] = 1.0f / colsum[tid]; }
    __syncthreads();
    const int t0 = blockIdx.y * 128;
    for (int idx = tid; idx < 128 * E_; idx += 256) {
        const int tt = idx >> 4, e = idx & 15;
        disp[idx] = expf(logits[(size_t)(t0 + tt) * E_ + e] - cm[e]) * cs[e];
    }
    __syncthreads();
    const int d = blockIdx.x * 256 + tid;
    float acc[E_];
    #pragma unroll
    for (int e = 0; e < E_; ++e) acc[e] = 0.0f;
    const float* xp = x + (size_t)t0 * D_ + d;
    for (int tt = 0; tt < 128; ++tt) {
        const float xv = xp[(size_t)tt * D_];
        const float* dr = &disp[tt * E_];
        #pragma unroll
        for (int e = 0; e < E_; ++e) acc[e] += dr[e] * xv;
    }
    #pragma unroll
    for (int e = 0; e < E_; ++e) atomicAdd(&slots[e * D_ + d], acc[e]);
}

// K4: h[e][j] = dot(slots[e], w1[e][j]) + b1[e][j]. Wave per j, 4 j per block.
__global__ __launch_bounds__(256) void k4_h(const float* __restrict__ slots,
                                            const float* __restrict__ w1,
                                            const float* __restrict__ b1,
                                            float* __restrict__ h) {
    const int e = blockIdx.x >> 9;            // / 512
    const int jbase = (blockIdx.x & 511) * 4;
    __shared__ float sl[D_];
    for (int i = threadIdx.x; i < D_; i += 256) sl[i] = slots[e * D_ + i];
    __syncthreads();
    const int wave = threadIdx.x >> 6, lane = threadIdx.x & 63;
    const int j = jbase + wave;
    const float4* wr = (const float4*)(w1 + ((size_t)e * H_ + j) * D_);
    const float4* sr = (const float4*)sl;
    float s = 0.0f;
    #pragma unroll
    for (int k = 0; k < 4; ++k) {
        float4 wv = wr[lane + 64 * k];
        float4 sv = sr[lane + 64 * k];
        s += wv.x * sv.x + wv.y * sv.y + wv.z * sv.z + wv.w * sv.w;
    }
    s = wave_sum(s);
    if (lane == 0) h[e * H_ + j] = s + b1[e * H_ + j];
}

// K5: LayerNorm + exact GELU per expert row of h. 16 blocks x 256.
__global__ __launch_bounds__(256) void k5_ln_gelu(const float* __restrict__ h,
                                                  const float* __restrict__ g,
                                                  const float* __restrict__ bb,
                                                  float* __restrict__ h2) {
    const int e = blockIdx.x, tid = threadIdx.x;
    float v[8];
    float s = 0.0f, ss = 0.0f;
    #pragma unroll
    for (int k = 0; k < 8; ++k) {
        v[k] = h[e * H_ + tid + 256 * k];
        s += v[k]; ss += v[k] * v[k];
    }
    s = wave_sum(s); ss = wave_sum(ss);
    __shared__ float rs[4], rss[4];
    if ((tid & 63) == 0) { rs[tid >> 6] = s; rss[tid >> 6] = ss; }
    __syncthreads();
    s = rs[0] + rs[1] + rs[2] + rs[3];
    ss = rss[0] + rss[1] + rss[2] + rss[3];
    const float mean = s * (1.0f / H_);
    const float var = ss * (1.0f / H_) - mean * mean;
    const float rstd = rsqrtf(var + 1e-5f);
    #pragma unroll
    for (int k = 0; k < 8; ++k) {
        const int i = tid + 256 * k;
        float y = (v[k] - mean) * rstd * g[e * H_ + i] + bb[e * H_ + i];
        h2[e * H_ + i] = 0.5f * y * (1.0f + erff(y * 0.70710678118654752f));
    }
}

// K6: slot_out[e][d] = dot(h2[e], w2[e][d]) + b2[e][d]. Wave per d.
__global__ __launch_bounds__(256) void k6_slotout(const float* __restrict__ h2,
                                                  const float* __restrict__ w2,
                                                  const float* __restrict__ b2,
                                                  float* __restrict__ slot_out) {
    const int e = blockIdx.x >> 8;            // / 256
    const int dbase = (blockIdx.x & 255) * 4;
    __shared__ float hl[H_];
    for (int i = threadIdx.x; i < H_; i += 256) hl[i] = h2[e * H_ + i];
    __syncthreads();
    const int wave = threadIdx.x >> 6, lane = threadIdx.x & 63;
    const int d = dbase + wave;
    const float4* wr = (const float4*)(w2 + ((size_t)e * D_ + d) * H_);
    const float4* hr = (const float4*)hl;
    float s = 0.0f;
    #pragma unroll
    for (int k = 0; k < 8; ++k) {
        float4 wv = wr[lane + 64 * k];
        float4 hv = hr[lane + 64 * k];
        s += wv.x * hv.x + wv.y * hv.y + wv.z * hv.z + wv.w * hv.w;
    }
    s = wave_sum(s);
    if (lane == 0) slot_out[e * D_ + d] = s + b2[e * D_ + d];
}

// K7: out[t][d] = sum_e combine[t][e] * slot_out[e][d]. 16 tokens per block.
__global__ __launch_bounds__(256) void k7_out(const float* __restrict__ combine,
                                              const float* __restrict__ slot_out,
                                              float* __restrict__ out) {
    const int tbase = blockIdx.x * 16;
    __shared__ float cl[256];
    cl[threadIdx.x] = combine[(size_t)tbase * E_ + threadIdx.x];
    __syncthreads();
    float4 so[E_];
    const float4* sr = (const float4*)slot_out;
    #pragma unroll
    for (int e = 0; e < E_; ++e) so[e] = sr[e * 256 + threadIdx.x];
    for (int tt = 0; tt < 16; ++tt) {
        float4 acc = { 0.0f, 0.0f, 0.0f, 0.0f };
        #pragma unroll
        for (int e = 0; e < E_; ++e) {
            const float c = cl[tt * E_ + e];
            acc.x += c * so[e].x; acc.y += c * so[e].y;
            acc.z += c * so[e].z; acc.w += c * so[e].w;
        }
        ((float4*)out)[(size_t)(tbase + tt) * 256 + threadIdx.x] = acc;
    }
}

// K8: router_loss + entropy scalars. 1 block.
__global__ __launch_bounds__(256) void k8_scalars(const float* __restrict__ rw,
                                                  const float* __restrict__ musum,
                                                  const float* __restrict__ entacc,
                                                  float* __restrict__ out_scalars) {
    const int tid = threadIdx.x, lane = tid & 63, wave = tid >> 6;
    __shared__ float red[4];
    __shared__ float rm[E_];
    for (int e = 0; e < E_; ++e) {
        float s = 0.0f;
        for (int i = tid; i < D_; i += 256) s += rw[e * D_ + i];
        s = wave_sum(s);
        if (lane == 0) red[wave] = s;
        __syncthreads();
        if (tid == 0) rm[e] = (red[0] + red[1] + red[2] + red[3]) * (1.0f / D_);
        __syncthreads();
    }
    if (tid == 0) {
        float m = rm[0];
        for (int e = 1; e < E_; ++e) m = fmaxf(m, rm[e]);
        float s = 0.0f, pe[E_];
        for (int e = 0; e < E_; ++e) { pe[e] = expf(rm[e] - m); s += pe[e]; }
        float loss = 0.0f;
        for (int e = 0; e < E_; ++e) loss += (musum[e] * (1.0f / T_)) * (pe[e] / s);
        loss *= (float)E_;
        out_scalars[0] = loss;
        out_scalars[1] = entacc[0] * (1.0f / T_);
    }
}

extern "C" void kernel_launch(void* const* d_in, const int* in_sizes, int n_in,
                              void* d_out, int out_size, void* d_ws, size_t ws_size,
                              hipStream_t stream) {
    const float* x    = (const float*)d_in[0];  // [T, D]
    const float* rw   = (const float*)d_in[1];  // [E, D]
    const float* w1   = (const float*)d_in[2];  // [E, H, D]
    const float* b1   = (const float*)d_in[3];  // [E, H]
    const float* ln_g = (const float*)d_in[4];  // [E, H]
    const float* ln_b = (const float*)d_in[5];  // [E, H]
    const float* w2   = (const float*)d_in[6];  // [E, D, H]
    const float* b2   = (const float*)d_in[7];  // [E, D]

    float* out = (float*)d_out;                 // [T*D] then loss, entropy
    float* wsf = (float*)d_ws;

    // workspace layout (floats)
    float* logits   = wsf;                       // 131072
    float* combine  = wsf + 131072;              // 131072
    float* colmax   = wsf + 262144;              // 16
    float* colsum   = wsf + 262160;              // 16
    float* h        = wsf + 262176;              // 32768
    float* h2       = wsf + 294944;              // 32768
    float* slot_out = wsf + 327712;              // 16384
    float* slots    = wsf + 344096;              // 16384
    float* musum    = wsf + 360480;              // 16
    float* entacc   = wsf + 360496;              // 1

    // zero the accumulator region (slots + musum + entacc, contiguous)
    hipMemsetAsync(slots, 0, (size_t)(16384 + 16 + 1) * sizeof(float), stream);

    k1_logits<<<T_ / 32, 256, 0, stream>>>(x, rw, logits);
    k2a_colstats<<<E_, 256, 0, stream>>>(logits, colmax, colsum);
    k2b_combine<<<T_ / 256, 256, 0, stream>>>(logits, combine, musum, entacc);
    k3_slots<<<dim3(4, 64), 256, 0, stream>>>(x, logits, colmax, colsum, slots);
    k4_h<<<E_ * 512, 256, 0, stream>>>(slots, w1, b1, h);
    k5_ln_gelu<<<E_, 256, 0, stream>>>(h, ln_g, ln_b, h2);
    k6_slotout<<<E_ * 256, 256, 0, stream>>>(h2, w2, b2, slot_out);
    k7_out<<<T_ / 16, 256, 0, stream>>>(combine, slot_out, out);
    k8_scalars<<<1, 256, 0, stream>>>(rw, musum, entacc, out + (size_t)T_ * D_);
}

// Round 3
// 388.708 us; speedup vs baseline: 1.1536x; 1.1536x over previous
//
#include <hip/hip_runtime.h>
#include <hip/hip_bf16.h>
#include <math.h>

// Problem constants
#define T_ 8192   // B*S tokens
#define D_ 1024
#define E_ 16
#define H_ 2048

typedef float f4 __attribute__((ext_vector_type(4)));

__device__ __forceinline__ float wave_sum(float v) {
    #pragma unroll
    for (int m = 32; m >= 1; m >>= 1) v += __shfl_xor(v, m, 64);
    return v;
}
__device__ __forceinline__ float wave_max(float v) {
    #pragma unroll
    for (int m = 32; m >= 1; m >>= 1) v = fmaxf(v, __shfl_xor(v, m, 64));
    return v;
}
__device__ __forceinline__ float grp16_sum(float v) {
    #pragma unroll
    for (int m = 8; m >= 1; m >>= 1) v += __shfl_xor(v, m, 16);
    return v;
}
__device__ __forceinline__ float grp16_max(float v) {
    #pragma unroll
    for (int m = 8; m >= 1; m >>= 1) v = fmaxf(v, __shfl_xor(v, m, 16));
    return v;
}

// K1 (fused): logits + per-token combine softmax + musum/entropy accumulation.
// 256 blocks x 256 threads; block stages router_w (64KB) in LDS; each wave
// handles 8 tokens. After the logits wave-reduce, lanes 0..15 hold the row ->
// width-16 shuffle softmax, no second pass over logits.
__global__ __launch_bounds__(256) void k1_logits_combine(const float* __restrict__ x,
                                                         const float* __restrict__ rw,
                                                         float* __restrict__ logits,
                                                         float* __restrict__ combine,
                                                         float* __restrict__ musum,
                                                         float* __restrict__ entacc) {
    __shared__ float rw_lds[E_ * D_];
    for (int i = threadIdx.x; i < E_ * D_; i += 256) rw_lds[i] = rw[i];
    __syncthreads();
    const int wave = threadIdx.x >> 6, lane = threadIdx.x & 63;
    const int t0 = blockIdx.x * 32 + wave * 8;
    const float4* rl = (const float4*)rw_lds;
    float mu_reg = 0.0f, ent_reg = 0.0f;
    for (int ti = 0; ti < 8; ++ti) {
        const int t = t0 + ti;
        const float4* xr = (const float4*)(x + (size_t)t * D_);
        float4 xv[4];
        #pragma unroll
        for (int k = 0; k < 4; ++k) xv[k] = xr[lane + 64 * k];
        float my = 0.0f;
        #pragma unroll
        for (int e = 0; e < E_; ++e) {
            float s = 0.0f;
            #pragma unroll
            for (int k = 0; k < 4; ++k) {
                float4 wv = rl[e * 256 + lane + 64 * k];
                s += xv[k].x * wv.x + xv[k].y * wv.y + xv[k].z * wv.z + xv[k].w * wv.w;
            }
            s = wave_sum(s);
            if (lane == e) my = s;
        }
        if (lane < E_) logits[(size_t)t * E_ + lane] = my;
        // row softmax across lanes 0..15 (other 16-lane groups compute garbage,
        // which stays within their own shuffle group and is masked below)
        float m = grp16_max(my);
        float cexp = expf(my - m);
        float ssum = grp16_sum(cexp);
        float c = cexp / ssum;
        if (lane < E_) {
            combine[(size_t)t * E_ + lane] = c;
            mu_reg += c;
        }
        float entc = (lane < E_) ? (-c * logf(c + 1e-8f)) : 0.0f;
        entc = grp16_sum(entc);
        if (lane == 0) ent_reg += entc;
    }
    if (lane < E_) atomicAdd(&musum[lane], mu_reg);
    if (lane == 0) atomicAdd(entacc, ent_reg);
}

// K2a: per-expert column max & sum(exp) over all T tokens. 16 blocks.
__global__ __launch_bounds__(256) void k2a_colstats(const float* __restrict__ logits,
                                                    float* __restrict__ colmax,
                                                    float* __restrict__ colsum) {
    const int e = blockIdx.x, tid = threadIdx.x;
    float m = -1e30f;
    for (int t = tid; t < T_; t += 256) m = fmaxf(m, logits[(size_t)t * E_ + e]);
    m = wave_max(m);
    __shared__ float red[4];
    if ((tid & 63) == 0) red[tid >> 6] = m;
    __syncthreads();
    m = fmaxf(fmaxf(red[0], red[1]), fmaxf(red[2], red[3]));
    __syncthreads();
    float s = 0.0f;
    for (int t = tid; t < T_; t += 256) s += expf(logits[(size_t)t * E_ + e] - m);
    s = wave_sum(s);
    if ((tid & 63) == 0) red[tid >> 6] = s;
    __syncthreads();
    if (tid == 0) {
        colmax[e] = m;
        colsum[e] = red[0] + red[1] + red[2] + red[3];
    }
}

// K3: slots[e][d] = sum_t dispatch[t][e] * x[t][d]
// grid (4 d-chunks, 64 t-chunks) x 256 threads; partial acc + atomicAdd.
// disp row reads are uniform-address float4 broadcasts (4 ds_read_b128/iter).
__global__ __launch_bounds__(256) void k3_slots(const float* __restrict__ x,
                                                const float* __restrict__ logits,
                                                const float* __restrict__ colmax,
                                                const float* __restrict__ colsum,
                                                float* __restrict__ slots) {
    const int tid = threadIdx.x;
    __shared__ float disp[128 * E_];
    __shared__ float cm[E_], cs[E_];
    if (tid < E_) { cm[tid] = colmax[tid]; cs[tid] = 1.0f / colsum[tid]; }
    __syncthreads();
    const int t0 = blockIdx.y * 128;
    for (int idx = tid; idx < 128 * E_; idx += 256) {
        const int tt = idx >> 4, e = idx & 15;
        disp[idx] = expf(logits[(size_t)(t0 + tt) * E_ + e] - cm[e]) * cs[e];
    }
    __syncthreads();
    const int d = blockIdx.x * 256 + tid;
    float acc[E_];
    #pragma unroll
    for (int e = 0; e < E_; ++e) acc[e] = 0.0f;
    const float* xp = x + (size_t)t0 * D_ + d;
    for (int tt = 0; tt < 128; ++tt) {
        const float xv = xp[(size_t)tt * D_];
        const float4* dr = (const float4*)&disp[tt * E_];
        float4 d0 = dr[0], d1 = dr[1], d2 = dr[2], d3 = dr[3];
        acc[0]  += d0.x * xv; acc[1]  += d0.y * xv; acc[2]  += d0.z * xv; acc[3]  += d0.w * xv;
        acc[4]  += d1.x * xv; acc[5]  += d1.y * xv; acc[6]  += d1.z * xv; acc[7]  += d1.w * xv;
        acc[8]  += d2.x * xv; acc[9]  += d2.y * xv; acc[10] += d2.z * xv; acc[11] += d2.w * xv;
        acc[12] += d3.x * xv; acc[13] += d3.y * xv; acc[14] += d3.z * xv; acc[15] += d3.w * xv;
    }
    #pragma unroll
    for (int e = 0; e < E_; ++e) atomicAdd(&slots[e * D_ + d], acc[e]);
}

// K4: h[e][j] = dot(slots[e], w1[e][j]) + b1[e][j].
// Wave per 4 rows; slots kept in 4 float4 regs per wave (no LDS, no barrier).
// grid = E * 128 blocks (16 rows/block).
__global__ __launch_bounds__(256) void k4_h(const float* __restrict__ slots,
                                            const float* __restrict__ w1,
                                            const float* __restrict__ b1,
                                            float* __restrict__ h) {
    const int e = blockIdx.x >> 7;
    const int jgrp = (blockIdx.x & 127) * 16;
    const int wave = threadIdx.x >> 6, lane = threadIdx.x & 63;
    const float4* sr = (const float4*)(slots + e * D_);
    float4 sv[4];
    #pragma unroll
    for (int k = 0; k < 4; ++k) sv[k] = sr[lane + 64 * k];
    #pragma unroll
    for (int r = 0; r < 4; ++r) {
        const int j = jgrp + wave * 4 + r;
        const f4* wr = (const f4*)(w1 + ((size_t)e * H_ + j) * D_);
        float s = 0.0f;
        #pragma unroll
        for (int k = 0; k < 4; ++k) {
            f4 wv = __builtin_nontemporal_load(&wr[lane + 64 * k]);
            s += wv.x * sv[k].x + wv.y * sv[k].y + wv.z * sv[k].z + wv.w * sv[k].w;
        }
        s = wave_sum(s);
        if (lane == 0) h[e * H_ + j] = s + b1[e * H_ + j];
    }
}

// K5: LayerNorm + exact GELU per expert row of h. 16 blocks x 256.
__global__ __launch_bounds__(256) void k5_ln_gelu(const float* __restrict__ h,
                                                  const float* __restrict__ g,
                                                  const float* __restrict__ bb,
                                                  float* __restrict__ h2) {
    const int e = blockIdx.x, tid = threadIdx.x;
    float v[8];
    float s = 0.0f, ss = 0.0f;
    #pragma unroll
    for (int k = 0; k < 8; ++k) {
        v[k] = h[e * H_ + tid + 256 * k];
        s += v[k]; ss += v[k] * v[k];
    }
    s = wave_sum(s); ss = wave_sum(ss);
    __shared__ float rs[4], rss[4];
    if ((tid & 63) == 0) { rs[tid >> 6] = s; rss[tid >> 6] = ss; }
    __syncthreads();
    s = rs[0] + rs[1] + rs[2] + rs[3];
    ss = rss[0] + rss[1] + rss[2] + rss[3];
    const float mean = s * (1.0f / H_);
    const float var = ss * (1.0f / H_) - mean * mean;
    const float rstd = rsqrtf(var + 1e-5f);
    #pragma unroll
    for (int k = 0; k < 8; ++k) {
        const int i = tid + 256 * k;
        float y = (v[k] - mean) * rstd * g[e * H_ + i] + bb[e * H_ + i];
        h2[e * H_ + i] = 0.5f * y * (1.0f + erff(y * 0.70710678118654752f));
    }
}

// K6: slot_out[e][d] = dot(h2[e], w2[e][d]) + b2[e][d].
// Wave per 4 d's; h2 kept in 8 float4 regs per wave. grid = E * 64 blocks.
__global__ __launch_bounds__(256) void k6_slotout(const float* __restrict__ h2,
                                                  const float* __restrict__ w2,
                                                  const float* __restrict__ b2,
                                                  float* __restrict__ slot_out) {
    const int e = blockIdx.x >> 6;
    const int dgrp = (blockIdx.x & 63) * 16;
    const int wave = threadIdx.x >> 6, lane = threadIdx.x & 63;
    const float4* hr = (const float4*)(h2 + e * H_);
    float4 hv[8];
    #pragma unroll
    for (int k = 0; k < 8; ++k) hv[k] = hr[lane + 64 * k];
    #pragma unroll
    for (int r = 0; r < 4; ++r) {
        const int d = dgrp + wave * 4 + r;
        const f4* wr = (const f4*)(w2 + ((size_t)e * D_ + d) * H_);
        float s = 0.0f;
        #pragma unroll
        for (int k = 0; k < 8; ++k) {
            f4 wv = __builtin_nontemporal_load(&wr[lane + 64 * k]);
            s += wv.x * hv[k].x + wv.y * hv[k].y + wv.z * hv[k].z + wv.w * hv[k].w;
        }
        s = wave_sum(s);
        if (lane == 0) slot_out[e * D_ + d] = s + b2[e * D_ + d];
    }
}

// K7: out[t][d] = sum_e combine[t][e] * slot_out[e][d]. 16 tokens per block.
__global__ __launch_bounds__(256) void k7_out(const float* __restrict__ combine,
                                              const float* __restrict__ slot_out,
                                              float* __restrict__ out) {
    const int tbase = blockIdx.x * 16;
    __shared__ float cl[256];
    cl[threadIdx.x] = combine[(size_t)tbase * E_ + threadIdx.x];
    __syncthreads();
    float4 so[E_];
    const float4* sr = (const float4*)slot_out;
    #pragma unroll
    for (int e = 0; e < E_; ++e) so[e] = sr[e * 256 + threadIdx.x];
    for (int tt = 0; tt < 16; ++tt) {
        float4 acc = { 0.0f, 0.0f, 0.0f, 0.0f };
        #pragma unroll
        for (int e = 0; e < E_; ++e) {
            const float c = cl[tt * E_ + e];
            acc.x += c * so[e].x; acc.y += c * so[e].y;
            acc.z += c * so[e].z; acc.w += c * so[e].w;
        }
        ((float4*)out)[(size_t)(tbase + tt) * 256 + threadIdx.x] = acc;
    }
}

// K8: router_loss + entropy scalars. 1 block; 4 waves x 4 experts in parallel.
__global__ __launch_bounds__(256) void k8_scalars(const float* __restrict__ rw,
                                                  const float* __restrict__ musum,
                                                  const float* __restrict__ entacc,
                                                  float* __restrict__ out_scalars) {
    const int tid = threadIdx.x, lane = tid & 63, wave = tid >> 6;
    __shared__ float rm[E_];
    #pragma unroll
    for (int q = 0; q < 4; ++q) {
        const int e = wave * 4 + q;
        const float4* rr = (const float4*)(rw + e * D_);
        float s = 0.0f;
        #pragma unroll
        for (int k = 0; k < 4; ++k) {
            float4 v = rr[lane * 4 + k];
            s += v.x + v.y + v.z + v.w;
        }
        s = wave_sum(s);
        if (lane == 0) rm[e] = s * (1.0f / D_);
    }
    __syncthreads();
    if (tid == 0) {
        float m = rm[0];
        for (int e = 1; e < E_; ++e) m = fmaxf(m, rm[e]);
        float s = 0.0f, pe[E_];
        for (int e = 0; e < E_; ++e) { pe[e] = expf(rm[e] - m); s += pe[e]; }
        float loss = 0.0f;
        for (int e = 0; e < E_; ++e) loss += (musum[e] * (1.0f / T_)) * (pe[e] / s);
        loss *= (float)E_;
        out_scalars[0] = loss;
        out_scalars[1] = entacc[0] * (1.0f / T_);
    }
}

extern "C" void kernel_launch(void* const* d_in, const int* in_sizes, int n_in,
                              void* d_out, int out_size, void* d_ws, size_t ws_size,
                              hipStream_t stream) {
    const float* x    = (const float*)d_in[0];  // [T, D]
    const float* rw   = (const float*)d_in[1];  // [E, D]
    const float* w1   = (const float*)d_in[2];  // [E, H, D]
    const float* b1   = (const float*)d_in[3];  // [E, H]
    const float* ln_g = (const float*)d_in[4];  // [E, H]
    const float* ln_b = (const float*)d_in[5];  // [E, H]
    const float* w2   = (const float*)d_in[6];  // [E, D, H]
    const float* b2   = (const float*)d_in[7];  // [E, D]

    float* out = (float*)d_out;                 // [T*D] then loss, entropy
    float* wsf = (float*)d_ws;

    // workspace layout (floats)
    float* logits   = wsf;                       // 131072
    float* combine  = wsf + 131072;              // 131072
    float* colmax   = wsf + 262144;              // 16
    float* colsum   = wsf + 262160;              // 16
    float* h        = wsf + 262176;              // 32768
    float* h2       = wsf + 294944;              // 32768
    float* slot_out = wsf + 327712;              // 16384
    float* slots    = wsf + 344096;              // 16384
    float* musum    = wsf + 360480;              // 16
    float* entacc   = wsf + 360496;              // 1

    // zero the accumulator region (slots + musum + entacc, contiguous)
    (void)hipMemsetAsync(slots, 0, (size_t)(16384 + 16 + 1) * sizeof(float), stream);

    k1_logits_combine<<<T_ / 32, 256, 0, stream>>>(x, rw, logits, combine, musum, entacc);
    k2a_colstats<<<E_, 256, 0, stream>>>(logits, colmax, colsum);
    k3_slots<<<dim3(4, 64), 256, 0, stream>>>(x, logits, colmax, colsum, slots);
    k4_h<<<E_ * 128, 256, 0, stream>>>(slots, w1, b1, h);
    k5_ln_gelu<<<E_, 256, 0, stream>>>(h, ln_g, ln_b, h2);
    k6_slotout<<<E_ * 64, 256, 0, stream>>>(h2, w2, b2, slot_out);
    k7_out<<<T_ / 16, 256, 0, stream>>>(combine, slot_out, out);
    k8_scalars<<<1, 256, 0, stream>>>(rw, musum, entacc, out + (size_t)T_ * D_);
}

// Round 4
// 368.214 us; speedup vs baseline: 1.2178x; 1.0557x over previous
//
#include <hip/hip_runtime.h>
#include <hip/hip_bf16.h>
#include <math.h>

// Problem constants
#define T_ 8192   // B*S tokens
#define D_ 1024
#define E_ 16
#define H_ 2048

typedef float f4 __attribute__((ext_vector_type(4)));

__device__ __forceinline__ float wave_sum(float v) {
    #pragma unroll
    for (int m = 32; m >= 1; m >>= 1) v += __shfl_xor(v, m, 64);
    return v;
}
__device__ __forceinline__ float grp16_sum(float v) {
    #pragma unroll
    for (int m = 8; m >= 1; m >>= 1) v += __shfl_xor(v, m, 16);
    return v;
}
__device__ __forceinline__ float grp16_max(float v) {
    #pragma unroll
    for (int m = 8; m >= 1; m >>= 1) v = fmaxf(v, __shfl_xor(v, m, 16));
    return v;
}

// K1 (fused): logits + combine softmax + musum/colsum/entropy accumulation.
// 512 blocks x 256 thr (2 blocks/CU; LDS 64KB). 16-lane group per token,
// 4 tokens per wave. grp16 reductions: 16 shfl/token (was 96).
// colsum is the UN-maxed token-softmax denominator (logits are |l|<~5, safe).
__global__ __launch_bounds__(256) void k1_logits_combine(const float* __restrict__ x,
                                                         const float* __restrict__ rw,
                                                         float* __restrict__ logits,
                                                         float* __restrict__ combine,
                                                         float* __restrict__ colsum,
                                                         float* __restrict__ musum,
                                                         float* __restrict__ entacc) {
    __shared__ float rw_lds[E_ * D_];
    for (int i = threadIdx.x; i < E_ * D_; i += 256) rw_lds[i] = rw[i];
    __syncthreads();
    const int lane = threadIdx.x & 63, wave = threadIdx.x >> 6;
    const int grp = lane >> 4, l16 = lane & 15;
    const int t = blockIdx.x * 16 + wave * 4 + grp;
    const f4* xr = (const f4*)(x + (size_t)t * D_);
    f4 xv[16];
    #pragma unroll
    for (int k = 0; k < 16; ++k) xv[k] = xr[l16 + 16 * k];
    const f4* rl = (const f4*)rw_lds;
    float my = 0.0f;
    #pragma unroll
    for (int e = 0; e < E_; ++e) {
        float s = 0.0f;
        #pragma unroll
        for (int k = 0; k < 16; ++k) {
            f4 wv = rl[e * 256 + l16 + 16 * k];
            s += wv.x * xv[k].x + wv.y * xv[k].y + wv.z * xv[k].z + wv.w * xv[k].w;
        }
        s = grp16_sum(s);
        if (l16 == e) my = s;
    }
    logits[(size_t)t * E_ + l16] = my;
    // combine softmax across the 16-lane group
    float m = grp16_max(my);
    float cexp = expf(my - m);
    float ssum = grp16_sum(cexp);
    float c = cexp / ssum;
    combine[(size_t)t * E_ + l16] = c;
    float ce = expf(my);                      // unnormalized dispatch numerator sum
    float ent = -c * logf(c + 1e-8f);
    float entt = grp16_sum(ent);              // token entropy (uniform in group)
    // cross-group sums (groups differ in lane bits 4..5)
    float mu = c;  mu += __shfl_xor(mu, 16, 64);  mu += __shfl_xor(mu, 32, 64);
    float cs = ce; cs += __shfl_xor(cs, 16, 64);  cs += __shfl_xor(cs, 32, 64);
    float et = entt; et += __shfl_xor(et, 16, 64); et += __shfl_xor(et, 32, 64);
    if (lane < E_) {
        atomicAdd(&musum[l16], mu);
        atomicAdd(&colsum[l16], cs);
    }
    if (lane == 0) atomicAdd(entacc, et);
}

// K3: slots[e][d] = sum_t (exp(l[t][e])/colsum[e]) * x[t][d]
// grid (4 d-chunks, 128 t-chunks of 64) x 256 threads; partials + atomicAdd.
__global__ __launch_bounds__(256) void k3_slots(const float* __restrict__ x,
                                                const float* __restrict__ logits,
                                                const float* __restrict__ colsum,
                                                float* __restrict__ slots) {
    const int tid = threadIdx.x;
    __shared__ float disp[64 * E_];
    __shared__ float cs[E_];
    if (tid < E_) cs[tid] = 1.0f / colsum[tid];
    __syncthreads();
    const int t0 = blockIdx.y * 64;
    for (int idx = tid; idx < 64 * E_; idx += 256) {
        disp[idx] = expf(logits[(size_t)t0 * E_ + idx]) * cs[idx & 15];
    }
    __syncthreads();
    const int d = blockIdx.x * 256 + tid;
    float acc[E_];
    #pragma unroll
    for (int e = 0; e < E_; ++e) acc[e] = 0.0f;
    const float* xp = x + (size_t)t0 * D_ + d;
    for (int tt = 0; tt < 64; ++tt) {
        const float xv = xp[(size_t)tt * D_];
        const float4* dr = (const float4*)&disp[tt * E_];
        float4 d0 = dr[0], d1 = dr[1], d2 = dr[2], d3 = dr[3];
        acc[0]  += d0.x * xv; acc[1]  += d0.y * xv; acc[2]  += d0.z * xv; acc[3]  += d0.w * xv;
        acc[4]  += d1.x * xv; acc[5]  += d1.y * xv; acc[6]  += d1.z * xv; acc[7]  += d1.w * xv;
        acc[8]  += d2.x * xv; acc[9]  += d2.y * xv; acc[10] += d2.z * xv; acc[11] += d2.w * xv;
        acc[12] += d3.x * xv; acc[13] += d3.y * xv; acc[14] += d3.z * xv; acc[15] += d3.w * xv;
    }
    #pragma unroll
    for (int e = 0; e < E_; ++e) atomicAdd(&slots[e * D_ + d], acc[e]);
}

// K4: h[e][j] = dot(slots[e], w1[e][j]) + b1[e][j]. Wave per 4 rows, register
// staged slots, nontemporal weight stream. Block 2048 = router scalars (ex-k8).
__global__ __launch_bounds__(256) void k4_h(const float* __restrict__ slots,
                                            const float* __restrict__ w1,
                                            const float* __restrict__ b1,
                                            float* __restrict__ h,
                                            const float* __restrict__ rw,
                                            const float* __restrict__ musum,
                                            const float* __restrict__ entacc,
                                            float* __restrict__ out_scalars) {
    const int wave = threadIdx.x >> 6, lane = threadIdx.x & 63;
    if (blockIdx.x == E_ * 128) {
        // router_loss + entropy scalars
        const int tid = threadIdx.x;
        __shared__ float rm[E_];
        #pragma unroll
        for (int q = 0; q < 4; ++q) {
            const int e = wave * 4 + q;
            const f4* rr = (const f4*)(rw + e * D_);
            float s = 0.0f;
            #pragma unroll
            for (int k = 0; k < 4; ++k) {
                f4 v = rr[lane * 4 + k];
                s += v.x + v.y + v.z + v.w;
            }
            s = wave_sum(s);
            if (lane == 0) rm[e] = s * (1.0f / D_);
        }
        __syncthreads();
        if (tid == 0) {
            float m = rm[0];
            for (int e = 1; e < E_; ++e) m = fmaxf(m, rm[e]);
            float s = 0.0f, pe[E_];
            for (int e = 0; e < E_; ++e) { pe[e] = expf(rm[e] - m); s += pe[e]; }
            float loss = 0.0f;
            for (int e = 0; e < E_; ++e) loss += (musum[e] * (1.0f / T_)) * (pe[e] / s);
            out_scalars[0] = loss * (float)E_;
            out_scalars[1] = entacc[0] * (1.0f / T_);
        }
        return;
    }
    const int e = blockIdx.x >> 7;
    const int jgrp = (blockIdx.x & 127) * 16;
    const f4* sr = (const f4*)(slots + e * D_);
    f4 sv[4];
    #pragma unroll
    for (int k = 0; k < 4; ++k) sv[k] = sr[lane + 64 * k];
    #pragma unroll
    for (int r = 0; r < 4; ++r) {
        const int j = jgrp + wave * 4 + r;
        const f4* wr = (const f4*)(w1 + ((size_t)e * H_ + j) * D_);
        float s = 0.0f;
        #pragma unroll
        for (int k = 0; k < 4; ++k) {
            f4 wv = __builtin_nontemporal_load(&wr[lane + 64 * k]);
            s += wv.x * sv[k].x + wv.y * sv[k].y + wv.z * sv[k].z + wv.w * sv[k].w;
        }
        s = wave_sum(s);
        if (lane == 0) h[e * H_ + j] = s + b1[e * H_ + j];
    }
}

// K6 (fused LN+GELU+GEMV): each wave loads the full h row (8KB), computes LN
// stats via wave_sum (redundant per wave, hidden under w2 stream), applies
// LN+GELU in-register, then does 4 dot products against w2.
__global__ __launch_bounds__(256) void k6_slotout(const float* __restrict__ h,
                                                  const float* __restrict__ g,
                                                  const float* __restrict__ bb,
                                                  const float* __restrict__ w2,
                                                  const float* __restrict__ b2,
                                                  float* __restrict__ slot_out) {
    const int e = blockIdx.x >> 6;
    const int dgrp = (blockIdx.x & 63) * 16;
    const int wave = threadIdx.x >> 6, lane = threadIdx.x & 63;
    const f4* hr = (const f4*)(h + e * H_);
    f4 hv[8];
    float s = 0.0f, ss = 0.0f;
    #pragma unroll
    for (int k = 0; k < 8; ++k) {
        hv[k] = hr[lane + 64 * k];
        s  += hv[k].x + hv[k].y + hv[k].z + hv[k].w;
        ss += hv[k].x * hv[k].x + hv[k].y * hv[k].y + hv[k].z * hv[k].z + hv[k].w * hv[k].w;
    }
    s = wave_sum(s); ss = wave_sum(ss);
    const float mean = s * (1.0f / H_);
    const float var = ss * (1.0f / H_) - mean * mean;
    const float rstd = rsqrtf(var + 1e-5f);
    const f4* gr = (const f4*)(g + e * H_);
    const f4* br = (const f4*)(bb + e * H_);
    #pragma unroll
    for (int k = 0; k < 8; ++k) {
        f4 g4 = gr[lane + 64 * k];
        f4 b4 = br[lane + 64 * k];
        float y;
        y = (hv[k].x - mean) * rstd * g4.x + b4.x; hv[k].x = 0.5f * y * (1.0f + erff(y * 0.70710678118654752f));
        y = (hv[k].y - mean) * rstd * g4.y + b4.y; hv[k].y = 0.5f * y * (1.0f + erff(y * 0.70710678118654752f));
        y = (hv[k].z - mean) * rstd * g4.z + b4.z; hv[k].z = 0.5f * y * (1.0f + erff(y * 0.70710678118654752f));
        y = (hv[k].w - mean) * rstd * g4.w + b4.w; hv[k].w = 0.5f * y * (1.0f + erff(y * 0.70710678118654752f));
    }
    #pragma unroll
    for (int r = 0; r < 4; ++r) {
        const int d = dgrp + wave * 4 + r;
        const f4* wr = (const f4*)(w2 + ((size_t)e * D_ + d) * H_);
        float acc = 0.0f;
        #pragma unroll
        for (int k = 0; k < 8; ++k) {
            f4 wv = __builtin_nontemporal_load(&wr[lane + 64 * k]);
            acc += wv.x * hv[k].x + wv.y * hv[k].y + wv.z * hv[k].z + wv.w * hv[k].w;
        }
        acc = wave_sum(acc);
        if (lane == 0) slot_out[e * D_ + d] = acc + b2[e * D_ + d];
    }
}

// K7: out[t][d] = sum_e combine[t][e] * slot_out[e][d]. 16 tokens per block.
__global__ __launch_bounds__(256) void k7_out(const float* __restrict__ combine,
                                              const float* __restrict__ slot_out,
                                              float* __restrict__ out) {
    const int tbase = blockIdx.x * 16;
    __shared__ float cl[256];
    cl[threadIdx.x] = combine[(size_t)tbase * E_ + threadIdx.x];
    __syncthreads();
    float4 so[E_];
    const float4* sr = (const float4*)slot_out;
    #pragma unroll
    for (int e = 0; e < E_; ++e) so[e] = sr[e * 256 + threadIdx.x];
    for (int tt = 0; tt < 16; ++tt) {
        float4 acc = { 0.0f, 0.0f, 0.0f, 0.0f };
        #pragma unroll
        for (int e = 0; e < E_; ++e) {
            const float c = cl[tt * E_ + e];
            acc.x += c * so[e].x; acc.y += c * so[e].y;
            acc.z += c * so[e].z; acc.w += c * so[e].w;
        }
        ((float4*)out)[(size_t)(tbase + tt) * 256 + threadIdx.x] = acc;
    }
}

extern "C" void kernel_launch(void* const* d_in, const int* in_sizes, int n_in,
                              void* d_out, int out_size, void* d_ws, size_t ws_size,
                              hipStream_t stream) {
    const float* x    = (const float*)d_in[0];  // [T, D]
    const float* rw   = (const float*)d_in[1];  // [E, D]
    const float* w1   = (const float*)d_in[2];  // [E, H, D]
    const float* b1   = (const float*)d_in[3];  // [E, H]
    const float* ln_g = (const float*)d_in[4];  // [E, H]
    const float* ln_b = (const float*)d_in[5];  // [E, H]
    const float* w2   = (const float*)d_in[6];  // [E, D, H]
    const float* b2   = (const float*)d_in[7];  // [E, D]

    float* out = (float*)d_out;                 // [T*D] then loss, entropy
    float* wsf = (float*)d_ws;

    // workspace layout (floats)
    float* logits   = wsf;                       // 131072
    float* combine  = wsf + 131072;              // 131072
    float* h        = wsf + 262144;              // 32768
    float* slot_out = wsf + 294912;              // 16384
    float* slots    = wsf + 311296;              // 16384  (zeroed region start)
    float* colsum   = wsf + 327680;              // 16
    float* musum    = wsf + 327696;              // 16
    float* entacc   = wsf + 327712;              // 1

    // zero the accumulator region (slots + colsum + musum + entacc, contiguous)
    (void)hipMemsetAsync(slots, 0, (size_t)(16384 + 16 + 16 + 1) * sizeof(float), stream);

    k1_logits_combine<<<T_ / 16, 256, 0, stream>>>(x, rw, logits, combine, colsum, musum, entacc);
    k3_slots<<<dim3(4, 128), 256, 0, stream>>>(x, logits, colsum, slots);
    k4_h<<<E_ * 128 + 1, 256, 0, stream>>>(slots, w1, b1, h, rw, musum, entacc, out + (size_t)T_ * D_);
    k6_slotout<<<E_ * 64, 256, 0, stream>>>(h, ln_g, ln_b, w2, b2, slot_out);
    k7_out<<<T_ / 16, 256, 0, stream>>>(combine, slot_out, out);
}